// Round 2
// baseline (7946.033 us; speedup 1.0000x reference)
//
#include <hip/hip_runtime.h>
#include <hip/hip_bf16.h>

typedef __bf16 bf16_t;
typedef __bf16 bf16x8 __attribute__((ext_vector_type(8)));
typedef float f32x4 __attribute__((ext_vector_type(4)));

#define B_   32
#define S_   512
#define E_   512
#define H_   1024
#define G3   3072
#define MTOT 16384  // B*S
#define NWG  64     // persistent scan workgroups

// ---------------- f32 -> bf16 conversion ----------------
__global__ __launch_bounds__(256) void cvt_f32_bf16(const float* __restrict__ src,
                                                    bf16_t* __restrict__ dst, int n) {
    int i = (blockIdx.x * 256 + threadIdx.x) * 8;
    if (i + 8 <= n) {
        float4 a = *(const float4*)(src + i);
        float4 b = *(const float4*)(src + i + 4);
        bf16x8 v;
        v[0] = (bf16_t)a.x; v[1] = (bf16_t)a.y; v[2] = (bf16_t)a.z; v[3] = (bf16_t)a.w;
        v[4] = (bf16_t)b.x; v[5] = (bf16_t)b.y; v[6] = (bf16_t)b.z; v[7] = (bf16_t)b.w;
        *(bf16x8*)(dst + i) = v;
    } else {
        for (; i < n; ++i) dst[i] = (bf16_t)src[i];
    }
}

__global__ __launch_bounds__(256) void zero_bf16(bf16_t* __restrict__ p, int n) {
    int i = (blockIdx.x * 256 + threadIdx.x) * 8;
    if (i + 8 <= n) {
        bf16x8 z;
        for (int j = 0; j < 8; ++j) z[j] = (bf16_t)0.f;
        *(bf16x8*)(p + i) = z;
    }
}

// ---------------- phase 1: xg = gather(emb,x) @ W_ih^T + b_ih ----------------
// M=16384, N=3072, K=512. Tile 128x128, BK=32, 4 waves (2x2 of 64x64).
__global__ __launch_bounds__(256) void xg_gemm(const int* __restrict__ x,
                                               const float* __restrict__ emb,
                                               const bf16_t* __restrict__ Wihb,
                                               const float* __restrict__ b_ih,
                                               bf16_t* __restrict__ xgb) {
    __shared__ __attribute__((aligned(16))) bf16_t As[128][40];  // pad stride 40 (80B)
    __shared__ __attribute__((aligned(16))) bf16_t Bs[128][40];

    const int tid  = threadIdx.x;
    const int lane = tid & 63, wave = tid >> 6;
    const int wm = wave >> 1, wn = wave & 1;
    const int c16 = lane & 15, r16 = lane >> 4;
    const int tileN = blockIdx.x, tileM = blockIdx.y;
    const int sr = tid >> 1;          // staging row 0..127
    const int sh = (tid & 1) * 16;    // staging col offset (16 elems)

    const int tok = x[tileM * 128 + sr];
    const float*  asrc = emb  + (size_t)tok * E_;
    const bf16_t* bsrc = Wihb + (size_t)(tileN * 128 + sr) * E_;

    f32x4 zero = {0.f, 0.f, 0.f, 0.f};
    f32x4 acc[4][4];
    for (int i = 0; i < 4; ++i)
        for (int j = 0; j < 4; ++j) acc[i][j] = zero;

    for (int kt = 0; kt < 16; ++kt) {
        const int k0 = kt * 32;
        float4 a0 = *(const float4*)(asrc + k0 + sh);
        float4 a1 = *(const float4*)(asrc + k0 + sh + 4);
        float4 a2 = *(const float4*)(asrc + k0 + sh + 8);
        float4 a3 = *(const float4*)(asrc + k0 + sh + 12);
        bf16x8 av0, av1;
        av0[0]=(bf16_t)a0.x; av0[1]=(bf16_t)a0.y; av0[2]=(bf16_t)a0.z; av0[3]=(bf16_t)a0.w;
        av0[4]=(bf16_t)a1.x; av0[5]=(bf16_t)a1.y; av0[6]=(bf16_t)a1.z; av0[7]=(bf16_t)a1.w;
        av1[0]=(bf16_t)a2.x; av1[1]=(bf16_t)a2.y; av1[2]=(bf16_t)a2.z; av1[3]=(bf16_t)a2.w;
        av1[4]=(bf16_t)a3.x; av1[5]=(bf16_t)a3.y; av1[6]=(bf16_t)a3.z; av1[7]=(bf16_t)a3.w;
        *(bf16x8*)&As[sr][sh]     = av0;
        *(bf16x8*)&As[sr][sh + 8] = av1;
        bf16x8 bv0 = *(const bf16x8*)(bsrc + k0 + sh);
        bf16x8 bv1 = *(const bf16x8*)(bsrc + k0 + sh + 8);
        *(bf16x8*)&Bs[sr][sh]     = bv0;
        *(bf16x8*)&Bs[sr][sh + 8] = bv1;
        __syncthreads();

        bf16x8 af[4], bfv[4];
#pragma unroll
        for (int mi = 0; mi < 4; ++mi)
            af[mi] = *(const bf16x8*)&As[wm * 64 + mi * 16 + c16][r16 * 8];
#pragma unroll
        for (int ni = 0; ni < 4; ++ni)
            bfv[ni] = *(const bf16x8*)&Bs[wn * 64 + ni * 16 + c16][r16 * 8];
#pragma unroll
        for (int mi = 0; mi < 4; ++mi)
#pragma unroll
            for (int ni = 0; ni < 4; ++ni)
                acc[mi][ni] = __builtin_amdgcn_mfma_f32_16x16x32_bf16(af[mi], bfv[ni], acc[mi][ni], 0, 0, 0);
        __syncthreads();
    }

#pragma unroll
    for (int ni = 0; ni < 4; ++ni) {
        const int col = tileN * 128 + wn * 64 + ni * 16 + c16;
        const float bi = b_ih[col];
#pragma unroll
        for (int mi = 0; mi < 4; ++mi) {
            const int R0 = tileM * 128 + wm * 64 + mi * 16 + r16 * 4;
#pragma unroll
            for (int r = 0; r < 4; ++r)
                xgb[(size_t)(R0 + r) * G3 + col] = (bf16_t)(acc[mi][ni][r] + bi);
        }
    }
}

// ---------------- phase 2: persistent GRU scan ----------------
// 64 WGs; WG owns 16 h-columns (48 gate rows of W_hh, streamed from L2).
// Per step: 4 waves K-split MFMA (M=32,N=48,K=256 each) -> LDS reduce -> gates
// -> write h (bf16 broadcast buf + fp32 out) -> flag barrier.
__global__ __launch_bounds__(256, 1) void gru_scan(
    const bf16_t* __restrict__ xgb,
    const bf16_t* __restrict__ Whhb,
    const float* __restrict__ b_hh,
    bf16_t* __restrict__ hbuf,
    float* __restrict__ out,
    float* __restrict__ state,
    int* __restrict__ flags) {
    __shared__ float red[4][32][49];  // 49-col stride breaks r16 bank aliasing
    const int tid = threadIdx.x, lane = tid & 63, wave = tid >> 6;
    const int c16 = lane & 15, r16 = lane >> 4;
    const int wg = blockIdx.x;
    const int j0 = wg * 16;
    const int kb = wave * 256;

    // B-operand row pointers (lane reads row j0+c16 of each gate block)
    const bf16_t* wrow0 = Whhb + (size_t)(j0 + c16) * H_ + kb + r16 * 8;
    const bf16_t* wrow1 = wrow0 + (size_t)H_ * H_;
    const bf16_t* wrow2 = wrow1 + (size_t)H_ * H_;

    // gate-phase mapping: thread owns (b0=tid>>4, jl) and (b1=b0+16, jl)
    const int jl = tid & 15;
    const int b0 = tid >> 4;
    const int b1 = b0 + 16;
    const int j  = j0 + jl;
    const float bhr = b_hh[j], bhz = b_hh[H_ + j], bhn = b_hh[2 * H_ + j];
    const bf16_t* xp0 = xgb + (size_t)b0 * S_ * G3 + j;
    const bf16_t* xp1 = xgb + (size_t)b1 * S_ * G3 + j;
    float* op0 = out + (size_t)b0 * S_ * H_ + j;
    float* op1 = out + (size_t)b1 * S_ * H_ + j;
    float hold0 = 0.f, hold1 = 0.f;

    for (int s = 0; s < S_; ++s) {
        const bf16_t* hrd = hbuf + (size_t)(s & 1) * (B_ * H_);
        bf16_t*       hwr = hbuf + (size_t)((s + 1) & 1) * (B_ * H_);

        f32x4 zero = {0.f, 0.f, 0.f, 0.f};
        f32x4 acc0[2], acc1[2], acc2[2];
        acc0[0] = acc0[1] = acc1[0] = acc1[1] = acc2[0] = acc2[1] = zero;
#pragma unroll
        for (int kk = 0; kk < 8; ++kk) {
            const int k = kb + kk * 32 + r16 * 8;
            bf16x8 a0 = *(const bf16x8*)(hrd + (size_t)c16 * H_ + k);
            bf16x8 a1 = *(const bf16x8*)(hrd + (size_t)(16 + c16) * H_ + k);
            bf16x8 bv0 = *(const bf16x8*)(wrow0 + kk * 32);
            bf16x8 bv1 = *(const bf16x8*)(wrow1 + kk * 32);
            bf16x8 bv2 = *(const bf16x8*)(wrow2 + kk * 32);
            acc0[0] = __builtin_amdgcn_mfma_f32_16x16x32_bf16(a0, bv0, acc0[0], 0, 0, 0);
            acc0[1] = __builtin_amdgcn_mfma_f32_16x16x32_bf16(a1, bv0, acc0[1], 0, 0, 0);
            acc1[0] = __builtin_amdgcn_mfma_f32_16x16x32_bf16(a0, bv1, acc1[0], 0, 0, 0);
            acc1[1] = __builtin_amdgcn_mfma_f32_16x16x32_bf16(a1, bv1, acc1[1], 0, 0, 0);
            acc2[0] = __builtin_amdgcn_mfma_f32_16x16x32_bf16(a0, bv2, acc2[0], 0, 0, 0);
            acc2[1] = __builtin_amdgcn_mfma_f32_16x16x32_bf16(a1, bv2, acc2[1], 0, 0, 0);
        }
#pragma unroll
        for (int m = 0; m < 2; ++m)
#pragma unroll
            for (int r = 0; r < 4; ++r) {
                const int bb = m * 16 + r16 * 4 + r;
                red[wave][bb][c16]      = acc0[m][r];
                red[wave][bb][16 + c16] = acc1[m][r];
                red[wave][bb][32 + c16] = acc2[m][r];
            }
        __syncthreads();

        // gate phase (2 outputs per thread)
        {
            float hr = red[0][b0][jl] + red[1][b0][jl] + red[2][b0][jl] + red[3][b0][jl] + bhr;
            float hz = red[0][b0][16 + jl] + red[1][b0][16 + jl] + red[2][b0][16 + jl] + red[3][b0][16 + jl] + bhz;
            float hn = red[0][b0][32 + jl] + red[1][b0][32 + jl] + red[2][b0][32 + jl] + red[3][b0][32 + jl] + bhn;
            float xr = (float)xp0[0], xz = (float)xp0[H_], xn = (float)xp0[2 * H_];
            float rg = 1.f / (1.f + __expf(-(xr + hr)));
            float zg = 1.f / (1.f + __expf(-(xz + hz)));
            float ng = tanhf(xn + rg * hn);
            float hnew = (1.f - zg) * ng + zg * hold0;
            op0[0] = hnew;
            hwr[b0 * H_ + j] = (bf16_t)hnew;
            hold0 = hnew;
            if (s == S_ - 1) state[b0 * H_ + j] = hnew;
        }
        {
            float hr = red[0][b1][jl] + red[1][b1][jl] + red[2][b1][jl] + red[3][b1][jl] + bhr;
            float hz = red[0][b1][16 + jl] + red[1][b1][16 + jl] + red[2][b1][16 + jl] + red[3][b1][16 + jl] + bhz;
            float hn = red[0][b1][32 + jl] + red[1][b1][32 + jl] + red[2][b1][32 + jl] + red[3][b1][32 + jl] + bhn;
            float xr = (float)xp1[0], xz = (float)xp1[H_], xn = (float)xp1[2 * H_];
            float rg = 1.f / (1.f + __expf(-(xr + hr)));
            float zg = 1.f / (1.f + __expf(-(xz + hz)));
            float ng = tanhf(xn + rg * hn);
            float hnew = (1.f - zg) * ng + zg * hold1;
            op1[0] = hnew;
            hwr[b1 * H_ + j] = (bf16_t)hnew;
            hold1 = hnew;
            if (s == S_ - 1) state[b1 * H_ + j] = hnew;
        }
        xp0 += G3; xp1 += G3; op0 += H_; op1 += H_;

        // ---- device-scope step barrier ----
        __threadfence();          // release this thread's h writes
        __syncthreads();          // all threads' writes drained (vmcnt 0) + red reads done
        if (tid == 0)
            __hip_atomic_store(&flags[wg * 32], s + 1, __ATOMIC_RELEASE, __HIP_MEMORY_SCOPE_AGENT);
        if (wave == 0) {
            for (;;) {
                int v = __hip_atomic_load(&flags[lane * 32], __ATOMIC_RELAXED, __HIP_MEMORY_SCOPE_AGENT);
                if (__all(v >= s + 1)) break;
                __builtin_amdgcn_s_sleep(1);
            }
        }
        __syncthreads();
        __threadfence();          // acquire: next-step h reads see fresh data
    }
}

// ---------------- phase 3: LayerNorm in place (wave per row) ----------------
__global__ __launch_bounds__(256) void ln_kernel(float* __restrict__ out,
                                                 const float* __restrict__ gamma,
                                                 const float* __restrict__ beta) {
    const int wave = threadIdx.x >> 6, lane = threadIdx.x & 63;
    const size_t row = (size_t)blockIdx.x * 4 + wave;
    float* p = out + row * H_;
    float4 v[4];
    float sum = 0.f, sq = 0.f;
#pragma unroll
    for (int i = 0; i < 4; ++i) {
        v[i] = *(const float4*)(p + i * 256 + lane * 4);
        sum += v[i].x + v[i].y + v[i].z + v[i].w;
        sq  += v[i].x * v[i].x + v[i].y * v[i].y + v[i].z * v[i].z + v[i].w * v[i].w;
    }
#pragma unroll
    for (int o = 32; o > 0; o >>= 1) {
        sum += __shfl_xor(sum, o);
        sq  += __shfl_xor(sq, o);
    }
    const float mean = sum * (1.f / 1024.f);
    const float var  = sq * (1.f / 1024.f) - mean * mean;
    const float inv  = rsqrtf(var + 1e-5f);
#pragma unroll
    for (int i = 0; i < 4; ++i) {
        const int c = i * 256 + lane * 4;
        float4 g4 = *(const float4*)(gamma + c);
        float4 b4 = *(const float4*)(beta + c);
        float4 y;
        y.x = (v[i].x - mean) * inv * g4.x + b4.x;
        y.y = (v[i].y - mean) * inv * g4.y + b4.y;
        y.z = (v[i].z - mean) * inv * g4.z + b4.z;
        y.w = (v[i].w - mean) * inv * g4.w + b4.w;
        *(float4*)(p + c) = y;
    }
}

// ---------------- launch ----------------
extern "C" void kernel_launch(void* const* d_in, const int* in_sizes, int n_in,
                              void* d_out, int out_size, void* d_ws, size_t ws_size,
                              hipStream_t stream) {
    const int*   x     = (const int*)d_in[0];
    const float* emb   = (const float*)d_in[1];
    const float* W_ih  = (const float*)d_in[2];
    const float* W_hh  = (const float*)d_in[3];
    const float* b_ih  = (const float*)d_in[4];
    const float* b_hh  = (const float*)d_in[5];
    const float* gamma = (const float*)d_in[6];
    const float* beta  = (const float*)d_in[7];
    float* out   = (float*)d_out;
    float* state = out + (size_t)MTOT * H_;

    char* ws = (char*)d_ws;
    bf16_t* Wihb = (bf16_t*)(ws);                      // 3,145,728 B (dead after xg_gemm)
    bf16_t* Whhb = (bf16_t*)(ws + 3145728);            // 6,291,456 B
    bf16_t* xgb  = (bf16_t*)(ws + 9437184);            // 100,663,296 B
    bf16_t* hbuf = (bf16_t*)(ws + 110100480);          // 2 x 32768 bf16
    int*    flags = (int*)ws;                          // reuses Wihb region post-xg_gemm

    cvt_f32_bf16<<<768,  256, 0, stream>>>(W_ih, Wihb, 1572864);
    cvt_f32_bf16<<<1536, 256, 0, stream>>>(W_hh, Whhb, 3145728);
    zero_bf16<<<16, 256, 0, stream>>>(hbuf, 32768);

    dim3 gg(24, 128);
    xg_gemm<<<gg, 256, 0, stream>>>(x, emb, Wihb, b_ih, xgb);

    // Wihb is dead now; its first 8 KB becomes the barrier flag array.
    hipMemsetAsync(flags, 0, NWG * 32 * sizeof(int), stream);

    gru_scan<<<NWG, 256, 0, stream>>>(xgb, Whhb, b_hh, hbuf, out, state, flags);

    ln_kernel<<<4096, 256, 0, stream>>>(out, gamma, beta);
}

// Round 3
// 3014.660 us; speedup vs baseline: 2.6358x; 2.6358x over previous
//
#include <hip/hip_runtime.h>
#include <hip/hip_bf16.h>

typedef __bf16 bf16_t;
typedef __bf16 bf16x8 __attribute__((ext_vector_type(8)));
typedef float f32x4 __attribute__((ext_vector_type(4)));

#define B_   32
#define S_   512
#define E_   512
#define H_   1024
#define G3   3072
#define MTOT 16384  // B*S
#define NWG  64     // persistent scan workgroups

// ---------------- f32 -> bf16 conversion ----------------
__global__ __launch_bounds__(256) void cvt_f32_bf16(const float* __restrict__ src,
                                                    bf16_t* __restrict__ dst, int n) {
    int i = (blockIdx.x * 256 + threadIdx.x) * 8;
    if (i + 8 <= n) {
        float4 a = *(const float4*)(src + i);
        float4 b = *(const float4*)(src + i + 4);
        bf16x8 v;
        v[0] = (bf16_t)a.x; v[1] = (bf16_t)a.y; v[2] = (bf16_t)a.z; v[3] = (bf16_t)a.w;
        v[4] = (bf16_t)b.x; v[5] = (bf16_t)b.y; v[6] = (bf16_t)b.z; v[7] = (bf16_t)b.w;
        *(bf16x8*)(dst + i) = v;
    } else {
        for (; i < n; ++i) dst[i] = (bf16_t)src[i];
    }
}

// zero h double-buffer with agent-scope stores (coherence point = L3)
__global__ __launch_bounds__(256) void zero_hbuf(unsigned long long* __restrict__ p, int n) {
    int i = blockIdx.x * 256 + threadIdx.x;
    if (i < n)
        __hip_atomic_store(p + i, 0ULL, __ATOMIC_RELAXED, __HIP_MEMORY_SCOPE_AGENT);
}

// ---------------- phase 1: xg = gather(emb,x) @ W_ih^T + b_ih ----------------
// M=16384, N=3072, K=512. Tile 128x128, BK=32, 4 waves (2x2 of 64x64).
// Output layout: xgs[s][wg=0..63][b=0..31][g*16+jl]  (scan-friendly, contiguous 3KB/WG/step)
__global__ __launch_bounds__(256) void xg_gemm(const int* __restrict__ x,
                                               const float* __restrict__ emb,
                                               const bf16_t* __restrict__ Wihb,
                                               const float* __restrict__ b_ih,
                                               bf16_t* __restrict__ xgs) {
    __shared__ __attribute__((aligned(16))) bf16_t As[128][40];
    __shared__ __attribute__((aligned(16))) bf16_t Bs[128][40];

    const int tid  = threadIdx.x;
    const int lane = tid & 63, wave = tid >> 6;
    const int wm = wave >> 1, wn = wave & 1;
    const int c16 = lane & 15, r16 = lane >> 4;
    const int tileN = blockIdx.x, tileM = blockIdx.y;
    const int sr = tid >> 1;
    const int sh = (tid & 1) * 16;

    const int tok = x[tileM * 128 + sr];
    const float*  asrc = emb  + (size_t)tok * E_;
    const bf16_t* bsrc = Wihb + (size_t)(tileN * 128 + sr) * E_;

    f32x4 zero = {0.f, 0.f, 0.f, 0.f};
    f32x4 acc[4][4];
    for (int i = 0; i < 4; ++i)
        for (int j = 0; j < 4; ++j) acc[i][j] = zero;

    for (int kt = 0; kt < 16; ++kt) {
        const int k0 = kt * 32;
        float4 a0 = *(const float4*)(asrc + k0 + sh);
        float4 a1 = *(const float4*)(asrc + k0 + sh + 4);
        float4 a2 = *(const float4*)(asrc + k0 + sh + 8);
        float4 a3 = *(const float4*)(asrc + k0 + sh + 12);
        bf16x8 av0, av1;
        av0[0]=(bf16_t)a0.x; av0[1]=(bf16_t)a0.y; av0[2]=(bf16_t)a0.z; av0[3]=(bf16_t)a0.w;
        av0[4]=(bf16_t)a1.x; av0[5]=(bf16_t)a1.y; av0[6]=(bf16_t)a1.z; av0[7]=(bf16_t)a1.w;
        av1[0]=(bf16_t)a2.x; av1[1]=(bf16_t)a2.y; av1[2]=(bf16_t)a2.z; av1[3]=(bf16_t)a2.w;
        av1[4]=(bf16_t)a3.x; av1[5]=(bf16_t)a3.y; av1[6]=(bf16_t)a3.z; av1[7]=(bf16_t)a3.w;
        *(bf16x8*)&As[sr][sh]     = av0;
        *(bf16x8*)&As[sr][sh + 8] = av1;
        bf16x8 bv0 = *(const bf16x8*)(bsrc + k0 + sh);
        bf16x8 bv1 = *(const bf16x8*)(bsrc + k0 + sh + 8);
        *(bf16x8*)&Bs[sr][sh]     = bv0;
        *(bf16x8*)&Bs[sr][sh + 8] = bv1;
        __syncthreads();

        bf16x8 af[4], bfv[4];
#pragma unroll
        for (int mi = 0; mi < 4; ++mi)
            af[mi] = *(const bf16x8*)&As[wm * 64 + mi * 16 + c16][r16 * 8];
#pragma unroll
        for (int ni = 0; ni < 4; ++ni)
            bfv[ni] = *(const bf16x8*)&Bs[wn * 64 + ni * 16 + c16][r16 * 8];
#pragma unroll
        for (int mi = 0; mi < 4; ++mi)
#pragma unroll
            for (int ni = 0; ni < 4; ++ni)
                acc[mi][ni] = __builtin_amdgcn_mfma_f32_16x16x32_bf16(af[mi], bfv[ni], acc[mi][ni], 0, 0, 0);
        __syncthreads();
    }

#pragma unroll
    for (int ni = 0; ni < 4; ++ni) {
        const int col = tileN * 128 + wn * 64 + ni * 16 + c16;
        const int g = col >> 10, jc = col & 1023;
        const int wgi = jc >> 4, jl = jc & 15;
        const float bi = b_ih[col];
#pragma unroll
        for (int mi = 0; mi < 4; ++mi) {
            const int R0 = tileM * 128 + wm * 64 + mi * 16 + r16 * 4;
#pragma unroll
            for (int r = 0; r < 4; ++r) {
                const int R = R0 + r, b = R >> 9, s = R & 511;
                xgs[(((size_t)s * NWG + wgi) * B_ + b) * 48 + g * 16 + jl] =
                    (bf16_t)(acc[mi][ni][r] + bi);
            }
        }
    }
}

// ---------------- phase 2: persistent GRU scan ----------------
// 64 WGs; WG owns 16 h-cols. Cross-WG shared data (h, flags) accessed ONLY via
// relaxed agent-scope atomics (sc1, coherence at L3) -> no fences, W_hh stays in L2.
__global__ __launch_bounds__(256, 1) void gru_scan(
    const bf16_t* __restrict__ xgs,
    const bf16_t* __restrict__ Whhb,
    const float* __restrict__ b_hh,
    bf16_t* __restrict__ hbuf,
    float* __restrict__ out,
    float* __restrict__ state,
    int* __restrict__ flags) {
    __shared__ float red[4][32][49];
    const int tid = threadIdx.x, lane = tid & 63, wave = tid >> 6;
    const int c16 = lane & 15, r16 = lane >> 4;
    const int wg = blockIdx.x;
    const int j0 = wg * 16;
    const int kb = wave * 256;

    const bf16_t* wrow0 = Whhb + (size_t)(j0 + c16) * H_ + kb + r16 * 8;
    const bf16_t* wrow1 = wrow0 + (size_t)H_ * H_;
    const bf16_t* wrow2 = wrow1 + (size_t)H_ * H_;

    // gate mapping: thread -> (batch bb, col pair pr)
    const int pr = tid & 7;
    const int bb = tid >> 3;
    const int jl = pr * 2;
    const int j  = j0 + jl;
    const float bhr0 = b_hh[j],          bhr1 = b_hh[j + 1];
    const float bhz0 = b_hh[H_ + j],     bhz1 = b_hh[H_ + j + 1];
    const float bhn0 = b_hh[2 * H_ + j], bhn1 = b_hh[2 * H_ + j + 1];

    const bf16_t* xgp = xgs + ((size_t)wg * B_ + bb) * 48;
    float* op = out + (size_t)bb * S_ * H_ + j;
    float h0 = 0.f, h1 = 0.f;

    for (int s = 0; s < S_; ++s) {
        const bf16_t* hrd = hbuf + (size_t)(s & 1) * (B_ * H_);
        bf16_t*       hwr = hbuf + (size_t)((s + 1) & 1) * (B_ * H_);

        f32x4 zero = {0.f, 0.f, 0.f, 0.f};
        f32x4 acc0[2], acc1[2], acc2[2];
        acc0[0] = acc0[1] = acc1[0] = acc1[1] = acc2[0] = acc2[1] = zero;
#pragma unroll
        for (int kk = 0; kk < 8; ++kk) {
            const int k = kb + kk * 32 + r16 * 8;
            const unsigned long long* pa0 = (const unsigned long long*)(hrd + (size_t)c16 * H_ + k);
            const unsigned long long* pa1 = (const unsigned long long*)(hrd + (size_t)(16 + c16) * H_ + k);
            union { unsigned long long u[2]; bf16x8 v; } A0, A1;
            A0.u[0] = __hip_atomic_load(pa0,     __ATOMIC_RELAXED, __HIP_MEMORY_SCOPE_AGENT);
            A0.u[1] = __hip_atomic_load(pa0 + 1, __ATOMIC_RELAXED, __HIP_MEMORY_SCOPE_AGENT);
            A1.u[0] = __hip_atomic_load(pa1,     __ATOMIC_RELAXED, __HIP_MEMORY_SCOPE_AGENT);
            A1.u[1] = __hip_atomic_load(pa1 + 1, __ATOMIC_RELAXED, __HIP_MEMORY_SCOPE_AGENT);
            bf16x8 bv0 = *(const bf16x8*)(wrow0 + kk * 32);
            bf16x8 bv1 = *(const bf16x8*)(wrow1 + kk * 32);
            bf16x8 bv2 = *(const bf16x8*)(wrow2 + kk * 32);
            acc0[0] = __builtin_amdgcn_mfma_f32_16x16x32_bf16(A0.v, bv0, acc0[0], 0, 0, 0);
            acc0[1] = __builtin_amdgcn_mfma_f32_16x16x32_bf16(A1.v, bv0, acc0[1], 0, 0, 0);
            acc1[0] = __builtin_amdgcn_mfma_f32_16x16x32_bf16(A0.v, bv1, acc1[0], 0, 0, 0);
            acc1[1] = __builtin_amdgcn_mfma_f32_16x16x32_bf16(A1.v, bv1, acc1[1], 0, 0, 0);
            acc2[0] = __builtin_amdgcn_mfma_f32_16x16x32_bf16(A0.v, bv2, acc2[0], 0, 0, 0);
            acc2[1] = __builtin_amdgcn_mfma_f32_16x16x32_bf16(A1.v, bv2, acc2[1], 0, 0, 0);
        }
#pragma unroll
        for (int m = 0; m < 2; ++m)
#pragma unroll
            for (int r = 0; r < 4; ++r) {
                const int bi = m * 16 + r16 * 4 + r;
                red[wave][bi][c16]      = acc0[m][r];
                red[wave][bi][16 + c16] = acc1[m][r];
                red[wave][bi][32 + c16] = acc2[m][r];
            }
        __syncthreads();

        // ---- gate phase: 2 adjacent columns for one batch ----
        float hr0 = red[0][bb][jl] + red[1][bb][jl] + red[2][bb][jl] + red[3][bb][jl] + bhr0;
        float hr1 = red[0][bb][jl+1] + red[1][bb][jl+1] + red[2][bb][jl+1] + red[3][bb][jl+1] + bhr1;
        float hz0 = red[0][bb][16+jl] + red[1][bb][16+jl] + red[2][bb][16+jl] + red[3][bb][16+jl] + bhz0;
        float hz1 = red[0][bb][17+jl] + red[1][bb][17+jl] + red[2][bb][17+jl] + red[3][bb][17+jl] + bhz1;
        float hn0 = red[0][bb][32+jl] + red[1][bb][32+jl] + red[2][bb][32+jl] + red[3][bb][32+jl] + bhn0;
        float hn1 = red[0][bb][33+jl] + red[1][bb][33+jl] + red[2][bb][33+jl] + red[3][bb][33+jl] + bhn1;

        union { unsigned int u; bf16_t b[2]; } xr, xz, xn;
        xr.u = *(const unsigned int*)(xgp + jl);
        xz.u = *(const unsigned int*)(xgp + 16 + jl);
        xn.u = *(const unsigned int*)(xgp + 32 + jl);

        float rg0 = 1.f / (1.f + __expf(-((float)xr.b[0] + hr0)));
        float rg1 = 1.f / (1.f + __expf(-((float)xr.b[1] + hr1)));
        float zg0 = 1.f / (1.f + __expf(-((float)xz.b[0] + hz0)));
        float zg1 = 1.f / (1.f + __expf(-((float)xz.b[1] + hz1)));
        float ng0 = tanhf((float)xn.b[0] + rg0 * hn0);
        float ng1 = tanhf((float)xn.b[1] + rg1 * hn1);
        float hnew0 = (1.f - zg0) * ng0 + zg0 * h0;
        float hnew1 = (1.f - zg1) * ng1 + zg1 * h1;

        float2 o2; o2.x = hnew0; o2.y = hnew1;
        *(float2*)op = o2;
        union { unsigned int u; bf16_t b[2]; } hp;
        hp.b[0] = (bf16_t)hnew0; hp.b[1] = (bf16_t)hnew1;
        __hip_atomic_store((unsigned int*)(hwr + (size_t)bb * H_ + j), hp.u,
                           __ATOMIC_RELAXED, __HIP_MEMORY_SCOPE_AGENT);
        if (s == S_ - 1) *(float2*)(state + (size_t)bb * H_ + j) = o2;
        h0 = hnew0; h1 = hnew1;
        xgp += (size_t)NWG * B_ * 48; op += H_;

        // ---- step barrier: syncthreads drains vmcnt(0) -> sc1 stores are at L3 ----
        __syncthreads();
        if (tid == 0)
            __hip_atomic_store(&flags[wg * 32], s + 1, __ATOMIC_RELAXED, __HIP_MEMORY_SCOPE_AGENT);
        if (wave == 0) {
            for (;;) {
                int v = __hip_atomic_load(&flags[lane * 32], __ATOMIC_RELAXED, __HIP_MEMORY_SCOPE_AGENT);
                if (__all(v >= s + 1)) break;
                __builtin_amdgcn_s_sleep(1);
            }
        }
        __syncthreads();
    }
}

// ---------------- phase 3: LayerNorm in place (wave per row) ----------------
__global__ __launch_bounds__(256) void ln_kernel(float* __restrict__ out,
                                                 const float* __restrict__ gamma,
                                                 const float* __restrict__ beta) {
    const int wave = threadIdx.x >> 6, lane = threadIdx.x & 63;
    const size_t row = (size_t)blockIdx.x * 4 + wave;
    float* p = out + row * H_;
    float4 v[4];
    float sum = 0.f, sq = 0.f;
#pragma unroll
    for (int i = 0; i < 4; ++i) {
        v[i] = *(const float4*)(p + i * 256 + lane * 4);
        sum += v[i].x + v[i].y + v[i].z + v[i].w;
        sq  += v[i].x * v[i].x + v[i].y * v[i].y + v[i].z * v[i].z + v[i].w * v[i].w;
    }
#pragma unroll
    for (int o = 32; o > 0; o >>= 1) {
        sum += __shfl_xor(sum, o);
        sq  += __shfl_xor(sq, o);
    }
    const float mean = sum * (1.f / 1024.f);
    const float var  = sq * (1.f / 1024.f) - mean * mean;
    const float inv  = rsqrtf(var + 1e-5f);
#pragma unroll
    for (int i = 0; i < 4; ++i) {
        const int c = i * 256 + lane * 4;
        float4 g4 = *(const float4*)(gamma + c);
        float4 b4 = *(const float4*)(beta + c);
        float4 y;
        y.x = (v[i].x - mean) * inv * g4.x + b4.x;
        y.y = (v[i].y - mean) * inv * g4.y + b4.y;
        y.z = (v[i].z - mean) * inv * g4.z + b4.z;
        y.w = (v[i].w - mean) * inv * g4.w + b4.w;
        *(float4*)(p + c) = y;
    }
}

// ---------------- launch ----------------
extern "C" void kernel_launch(void* const* d_in, const int* in_sizes, int n_in,
                              void* d_out, int out_size, void* d_ws, size_t ws_size,
                              hipStream_t stream) {
    const int*   x     = (const int*)d_in[0];
    const float* emb   = (const float*)d_in[1];
    const float* W_ih  = (const float*)d_in[2];
    const float* W_hh  = (const float*)d_in[3];
    const float* b_ih  = (const float*)d_in[4];
    const float* b_hh  = (const float*)d_in[5];
    const float* gamma = (const float*)d_in[6];
    const float* beta  = (const float*)d_in[7];
    float* out   = (float*)d_out;
    float* state = out + (size_t)MTOT * H_;

    char* ws = (char*)d_ws;
    bf16_t* Wihb = (bf16_t*)(ws);                      // 3,145,728 B (dead after xg_gemm)
    bf16_t* Whhb = (bf16_t*)(ws + 3145728);            // 6,291,456 B
    bf16_t* xgs  = (bf16_t*)(ws + 9437184);            // 100,663,296 B
    bf16_t* hbuf = (bf16_t*)(ws + 110100480);          // 2 x 32768 bf16
    int*    flags = (int*)ws;                          // reuses Wihb region post-xg_gemm

    cvt_f32_bf16<<<768,  256, 0, stream>>>(W_ih, Wihb, 1572864);
    cvt_f32_bf16<<<1536, 256, 0, stream>>>(W_hh, Whhb, 3145728);
    zero_hbuf<<<64, 256, 0, stream>>>((unsigned long long*)hbuf, 16384);

    dim3 gg(24, 128);
    xg_gemm<<<gg, 256, 0, stream>>>(x, emb, Wihb, b_ih, xgs);

    hipMemsetAsync(flags, 0, NWG * 32 * sizeof(int), stream);

    gru_scan<<<NWG, 256, 0, stream>>>(xgs, Whhb, b_hh, hbuf, out, state, flags);

    ln_kernel<<<4096, 256, 0, stream>>>(out, gamma, beta);
}